// Round 12
// baseline (85.312 us; speedup 1.0000x reference)
//
#include <hip/hip_runtime.h>
#include <stdint.h>

typedef unsigned int  uint32;
typedef unsigned long long u64;

#define L2E 1.44269504088896340736f

typedef float f32x4 __attribute__((ext_vector_type(4)));
typedef short bf16x8 __attribute__((ext_vector_type(8)));

__device__ __forceinline__ unsigned short f2bf(float f){
  uint32 u = __float_as_uint(f);
  u += 0x7fffu + ((u >> 16) & 1u);
  return (unsigned short)(u >> 16);
}

// k-permutation: k' -> j:  Q = k'>>8, p = (k'>>6)&3, l = k'&63, j = Q*256 + 4*l + p
// inverse:       j  -> k': Q = j>>8,  l = (j&255)>>2, p = j&3,  k' = Q*256 + p*64 + l
// mask word w of row i: bit l <-> k' = w*64+l <-> j = (w>>2)*256 + 4*l + (w&3)
// gTp fragment layout: element (b, o, k') at
//   ((b*64 + (k'>>5))*8 + (o>>4))*512 + (((k'>>3)&3)*16 + (o&15))*8 + (k'&7)

// ---------------- K0: pure grid-stride streaming adj -> bitmask (m13 pattern) ----------------
// 2048 blocks x 256 thr = 524288 threads; 16 iterations x 524288 f32x4 = 8,388,608 = all of adj.
__global__ __launch_bounds__(256) void k_mask(const float* __restrict__ adj,
                                              u64* __restrict__ mask){
  const int lane = threadIdx.x & 63;
  const size_t t = (size_t)blockIdx.x * 256 + threadIdx.x;   // 0..524287
  const f32x4* ap = (const f32x4*)adj;
  #pragma unroll 4
  for (int it = 0; it < 16; ++it){
    size_t n = (size_t)it * 524288 + t;
    f32x4 av = ap[n];
    u64 b0 = __ballot(av[0] != 0.f);
    u64 b1 = __ballot(av[1] != 0.f);
    u64 b2 = __ballot(av[2] != 0.f);
    u64 b3 = __ballot(av[3] != 0.f);
    if (lane == 0){
      size_t nb = n & ~(size_t)63;
      size_t row = nb >> 9;                 // global flattened row (b*2048+i)
      int c = (int)((nb >> 6) & 7);         // 256-j chunk within row
      ulonglong2* dst = (ulonglong2*)(mask + row * 32 + c * 4);
      dst[0] = (ulonglong2){b0, b1};
      dst[1] = (ulonglong2){b2, b3};
    }
  }
}

// ---------------- K1: h = x @ W^T (bf16 split MFMA) + fused E1/E2p epilogue ----------------
__global__ __launch_bounds__(256) void k_h(const float* __restrict__ x,
                                           const float* __restrict__ W,
                                           const float* __restrict__ a1,
                                           const float* __restrict__ a2,
                                           const float* __restrict__ ab,
                                           float* __restrict__ h,
                                           float* __restrict__ E1,
                                           float* __restrict__ E2p){
  __shared__ unsigned short xs[2][64][72];    // [hi/lo][row][f] pad 72
  __shared__ unsigned short wsm[2][128][72];  // [hi/lo][o][f]
  const int tid = threadIdx.x;
  const int wv = tid >> 6, lane = tid & 63;
  const int r = lane & 15, kg = lane >> 4;
  const int row0 = blockIdx.x * 64;

  f32x4 acc[8];
  #pragma unroll
  for (int of = 0; of < 8; ++of) acc[of] = (f32x4){0.f,0.f,0.f,0.f};

  for (int kc = 0; kc < 4; ++kc){
    if (kc) __syncthreads();
    #pragma unroll
    for (int it = 0; it < 4; ++it){
      int idx = tid + it * 256;
      int row = idx >> 4, f = (idx & 15) * 4;
      float4 v = *(const float4*)(x + (size_t)(row0 + row) * 256 + kc * 64 + f);
      ushort4 hi, lo;
      { unsigned short hh = f2bf(v.x); float rr = v.x - __uint_as_float(((uint32)hh)<<16); hi.x = hh; lo.x = f2bf(rr); }
      { unsigned short hh = f2bf(v.y); float rr = v.y - __uint_as_float(((uint32)hh)<<16); hi.y = hh; lo.y = f2bf(rr); }
      { unsigned short hh = f2bf(v.z); float rr = v.z - __uint_as_float(((uint32)hh)<<16); hi.z = hh; lo.z = f2bf(rr); }
      { unsigned short hh = f2bf(v.w); float rr = v.w - __uint_as_float(((uint32)hh)<<16); hi.w = hh; lo.w = f2bf(rr); }
      *(ushort4*)&xs[0][row][f] = hi;
      *(ushort4*)&xs[1][row][f] = lo;
    }
    #pragma unroll
    for (int it = 0; it < 8; ++it){
      int idx = tid + it * 256;
      int o = idx >> 4, f = (idx & 15) * 4;
      float4 v = *(const float4*)(W + (size_t)o * 256 + kc * 64 + f);
      ushort4 hi, lo;
      { unsigned short hh = f2bf(v.x); float rr = v.x - __uint_as_float(((uint32)hh)<<16); hi.x = hh; lo.x = f2bf(rr); }
      { unsigned short hh = f2bf(v.y); float rr = v.y - __uint_as_float(((uint32)hh)<<16); hi.y = hh; lo.y = f2bf(rr); }
      { unsigned short hh = f2bf(v.z); float rr = v.z - __uint_as_float(((uint32)hh)<<16); hi.z = hh; lo.z = f2bf(rr); }
      { unsigned short hh = f2bf(v.w); float rr = v.w - __uint_as_float(((uint32)hh)<<16); hi.w = hh; lo.w = f2bf(rr); }
      *(ushort4*)&wsm[0][o][f] = hi;
      *(ushort4*)&wsm[1][o][f] = lo;
    }
    __syncthreads();
    #pragma unroll
    for (int kk = 0; kk < 2; ++kk){
      bf16x8 ah = *(const bf16x8*)&xs[0][wv*16 + r][kk*32 + kg*8];
      bf16x8 al = *(const bf16x8*)&xs[1][wv*16 + r][kk*32 + kg*8];
      #pragma unroll
      for (int of = 0; of < 8; ++of){
        bf16x8 bh = *(const bf16x8*)&wsm[0][of*16 + r][kk*32 + kg*8];
        bf16x8 bl = *(const bf16x8*)&wsm[1][of*16 + r][kk*32 + kg*8];
        acc[of] = __builtin_amdgcn_mfma_f32_16x16x32_bf16(ah, bh, acc[of], 0, 0, 0);
        acc[of] = __builtin_amdgcn_mfma_f32_16x16x32_bf16(ah, bl, acc[of], 0, 0, 0);
        acc[of] = __builtin_amdgcn_mfma_f32_16x16x32_bf16(al, bh, acc[of], 0, 0, 0);
      }
    }
  }
  #pragma unroll
  for (int of = 0; of < 8; ++of)
    #pragma unroll
    for (int q = 0; q < 4; ++q)
      h[(size_t)(row0 + wv*16 + kg*4 + q) * 128 + of*16 + r] = acc[of][q];

  float p1[4] = {0,0,0,0}, p2[4] = {0,0,0,0};
  #pragma unroll
  for (int of = 0; of < 8; ++of){
    float w1 = a1[of*16 + r], w2 = a2[of*16 + r];
    #pragma unroll
    for (int q = 0; q < 4; ++q){
      p1[q] = fmaf(acc[of][q], w1, p1[q]);
      p2[q] = fmaf(acc[of][q], w2, p2[q]);
    }
  }
  #pragma unroll
  for (int off = 8; off; off >>= 1)
    #pragma unroll
    for (int q = 0; q < 4; ++q){
      p1[q] += __shfl_xor(p1[q], off);
      p2[q] += __shfl_xor(p2[q], off);
    }
  if (r == 0){
    float abv = ab[0];
    #pragma unroll
    for (int q = 0; q < 4; ++q){
      int row = row0 + wv*16 + kg*4 + q;
      E1[row] = p1[q] * L2E;
      int bb = row >> 11, j = row & 2047;
      int kp = (j & ~255) + (j & 3) * 64 + ((j & 255) >> 2);
      E2p[bb * 2048 + kp] = (p2[q] + abv) * L2E;
    }
  }
}

// ---------------- K2: mask-driven denom partials (k'-order) ----------------
// grid (wg=8, ch=16, b=8); wave wv -> word w = wg*4+wv; lane l -> k' = w*64+l.
__global__ __launch_bounds__(256) void k_den(const u64* __restrict__ mask,
                                             const float* __restrict__ E1,
                                             const float* __restrict__ E2p,
                                             float* __restrict__ denomK){
  const int wg = blockIdx.x, ch = blockIdx.y, b = blockIdx.z;
  const int wv = threadIdx.x >> 6, lane = threadIdx.x & 63;
  const int w = wg * 4 + wv;
  const float e2 = E2p[b * 2048 + w * 64 + lane];
  const u64 lmask = 1ull << lane;
  const float* e1p = E1 + b * 2048 + ch * 128;
  const u64* mpp = mask + (size_t)(b * 2048 + ch * 128) * 32 + w;

  float acc = 0.f;
  #pragma unroll 8
  for (int i = 0; i < 128; ++i){
    u64 wb = mpp[(size_t)i * 32];
    float e1 = e1p[i];
    float t = e1 + e2;
    t = fmaxf(t, 0.2f * t);
    float v = __builtin_amdgcn_exp2f(t);
    acc += (wb & lmask) ? v : 0.f;
  }
  denomK[(size_t)ch * 16384 + b * 2048 + w * 64 + lane] = acc;
}

// ---------------- K3: gTp[frag-order] = bf16( h[b][j(k')][o] / denom_j ) ----------------
// grid (Q=8, ot=4, b=8); denomK is k'-indexed -> convert j->k' when summing.
__global__ __launch_bounds__(256) void k_gt(const float* __restrict__ h,
                                            const float* __restrict__ denomK,
                                            unsigned short* __restrict__ gTp){
  __shared__ float hl[8464];   // index: j*33 + (j>>4) + oo,  oo<32 (local node order)
  __shared__ float rrec[256];
  const int b = blockIdx.z, Q = blockIdx.x, ot = blockIdx.y;
  const int o0 = ot * 32;
  const int tid = threadIdx.x;

  {
    const int kpl = (tid & 3) * 64 + (tid >> 2);   // k' local of j local = tid
    float d = 0.f;
    #pragma unroll
    for (int ch = 0; ch < 16; ++ch)
      d += denomK[(size_t)ch * 16384 + b * 2048 + Q * 256 + kpl];
    rrec[tid] = 1.0f / d;
  }
  __syncthreads();

  #pragma unroll
  for (int it = 0; it < 8; ++it){
    int idx = tid + it * 256;
    int j = idx >> 3, f = idx & 7;
    float4 v = *(const float4*)(h + (size_t)(b * 2048 + Q * 256 + j) * 128 + o0 + f * 4);
    float rc = rrec[j];
    int base = j * 33 + (j >> 4) + f * 4;
    hl[base + 0] = v.x * rc;
    hl[base + 1] = v.y * rc;
    hl[base + 2] = v.z * rc;
    hl[base + 3] = v.w * rc;
  }
  __syncthreads();

  const int u  = tid & 127;
  const int fh = tid >> 7;
  const int lane = u >> 1;
  const int e0 = (u & 1) * 4;
  const int orow_r = lane & 15;
  const int kgrp = lane >> 4;
  #pragma unroll
  for (int it = 0; it < 8; ++it){
    int f  = it * 2 + fh;
    int kb = f >> 1, sl = f & 1;
    int orow = sl * 16 + orow_r;
    int klb = kb * 32 + kgrp * 8 + e0;
    ushort4 uu;
    { int kl = klb + 0; int jl = 4 * (kl & 63) + (kl >> 6); uu.x = f2bf(hl[jl * 33 + (jl >> 4) + orow]); }
    { int kl = klb + 1; int jl = 4 * (kl & 63) + (kl >> 6); uu.y = f2bf(hl[jl * 33 + (jl >> 4) + orow]); }
    { int kl = klb + 2; int jl = 4 * (kl & 63) + (kl >> 6); uu.z = f2bf(hl[jl * 33 + (jl >> 4) + orow]); }
    { int kl = klb + 3; int jl = 4 * (kl & 63) + (kl >> 6); uu.w = f2bf(hl[jl * 33 + (jl >> 4) + orow]); }
    size_t dst = ((size_t)((b * 64 + Q * 8 + kb) * 8 + (ot * 2 + sl))) * 512 + lane * 8 + e0;
    *(ushort4*)(gTp + dst) = uu;
  }
}

// ---------------- K4: out = ELU( A @ g ), A synthesized, B coalesced frag loads ----------------
__global__ __launch_bounds__(256) void k_main(const float* __restrict__ E1,
                                              const float* __restrict__ E2p,
                                              const uint32* __restrict__ mask32,
                                              const unsigned short* __restrict__ gTp,
                                              float* __restrict__ out){
  __shared__ float cmb[4][32][129];
  const int b  = blockIdx.y;
  const int ib = blockIdx.x;
  const int wv = threadIdx.x >> 6, lane = threadIdx.x & 63;
  const int r  = lane & 15, kg = lane >> 4;
  const int gi0 = b * 2048 + ib * 32 + r;
  const float e1_0 = E1[gi0];
  const float e1_1 = E1[gi0 + 16];
  const uint32* m0 = mask32 + (size_t)gi0 * 64;
  const uint32* m1 = mask32 + (size_t)(gi0 + 16) * 64;

  f32x4 acc[2][8];
  #pragma unroll
  for (int si = 0; si < 2; ++si)
    #pragma unroll
    for (int so = 0; so < 8; ++so)
      acc[si][so] = (f32x4){0.f, 0.f, 0.f, 0.f};

  const int k0 = wv * 512, k1 = k0 + 512;
  for (int kk = k0; kk < k1; kk += 32){
    const int j0 = kk + kg * 8;
    const float4 eA = *(const float4*)(E2p + b * 2048 + j0);
    const float4 eB = *(const float4*)(E2p + b * 2048 + j0 + 4);
    const uint32 bits0 = (m0[kk >> 5] >> (kg * 8)) & 0xffu;
    const uint32 bits1 = (m1[kk >> 5] >> (kg * 8)) & 0xffu;
    float e2v[8] = {eA.x, eA.y, eA.z, eA.w, eB.x, eB.y, eB.z, eB.w};

    union { uint32 u[4]; bf16x8 v; } af0, af1;
    #pragma unroll
    for (int p = 0; p < 4; ++p){
      {
        float t0 = e1_0 + e2v[2*p];     t0 = fmaxf(t0, 0.2f * t0);
        float t1 = e1_0 + e2v[2*p+1];   t1 = fmaxf(t1, 0.2f * t1);
        float x0 = ((bits0 >> (2*p))   & 1u) ? __builtin_amdgcn_exp2f(t0) : 0.f;
        float x1 = ((bits0 >> (2*p+1)) & 1u) ? __builtin_amdgcn_exp2f(t1) : 0.f;
        uint32 u0 = __float_as_uint(x0); u0 = (u0 + 0x7fffu + ((u0 >> 16) & 1u)) >> 16;
        uint32 u1 = __float_as_uint(x1); u1 = (u1 + 0x7fffu + ((u1 >> 16) & 1u)) & 0xffff0000u;
        af0.u[p] = u0 | u1;
      }
      {
        float t0 = e1_1 + e2v[2*p];     t0 = fmaxf(t0, 0.2f * t0);
        float t1 = e1_1 + e2v[2*p+1];   t1 = fmaxf(t1, 0.2f * t1);
        float x0 = ((bits1 >> (2*p))   & 1u) ? __builtin_amdgcn_exp2f(t0) : 0.f;
        float x1 = ((bits1 >> (2*p+1)) & 1u) ? __builtin_amdgcn_exp2f(t1) : 0.f;
        uint32 u0 = __float_as_uint(x0); u0 = (u0 + 0x7fffu + ((u0 >> 16) & 1u)) >> 16;
        uint32 u1 = __float_as_uint(x1); u1 = (u1 + 0x7fffu + ((u1 >> 16) & 1u)) & 0xffff0000u;
        af1.u[p] = u0 | u1;
      }
    }
    const unsigned short* gk = gTp + ((size_t)(b * 64 + (kk >> 5)) * 8) * 512 + lane * 8;
    #pragma unroll
    for (int so = 0; so < 8; ++so){
      bf16x8 bfr = *(const bf16x8*)(gk + so * 512);
      acc[0][so] = __builtin_amdgcn_mfma_f32_16x16x32_bf16(af0.v, bfr, acc[0][so], 0, 0, 0);
      acc[1][so] = __builtin_amdgcn_mfma_f32_16x16x32_bf16(af1.v, bfr, acc[1][so], 0, 0, 0);
    }
  }

  #pragma unroll
  for (int si = 0; si < 2; ++si)
    #pragma unroll
    for (int so = 0; so < 8; ++so)
      #pragma unroll
      for (int q = 0; q < 4; ++q){
        int il = si * 16 + kg * 4 + q;
        int o  = so * 16 + r;
        cmb[wv][il][o] = acc[si][so][q];
      }
  __syncthreads();
  for (int e = threadIdx.x; e < 4096; e += 256){
    int i = e >> 7, o = e & 127;
    float v = cmb[0][i][o] + cmb[1][i][o] + cmb[2][i][o] + cmb[3][i][o];
    float res = v > 0.f ? v : (__builtin_amdgcn_exp2f(v * L2E) - 1.0f);
    out[(size_t)(b * 2048 + ib * 32 + i) * 128 + o] = res;
  }
}

// ---------------- launch ----------------
extern "C" void kernel_launch(void* const* d_in, const int* in_sizes, int n_in,
                              void* d_out, int out_size, void* d_ws, size_t ws_size,
                              hipStream_t stream){
  const float* x   = (const float*)d_in[0];
  const float* adj = (const float*)d_in[1];
  const float* W   = (const float*)d_in[2];
  const float* a1  = (const float*)d_in[3];
  const float* a2  = (const float*)d_in[4];
  const float* ab  = (const float*)d_in[5];
  float* out = (float*)d_out;

  // ws layout (bytes):
  //   h      f32 [16384*128]      @ 0          (8,388,608)
  //   E1     f32 [16384]          @ 8388608    (65,536)
  //   E2p    f32 [16384]          @ 8454144    (65,536)
  //   denomK f32 [16][16384]      @ 8519680    (1,048,576)
  //   mask   u64 [8*2048*32]      @ 9568256    (4,194,304)
  //   gTp    bf16[8*64*8*512]     @ 13762560   (4,194,304)
  const size_t WS_NEEDED = 17956864;
  if (ws_size < WS_NEEDED) return;

  char* ws = (char*)d_ws;
  float* h      = (float*)(ws);
  float* E1     = (float*)(ws + 8388608);
  float* E2p    = (float*)(ws + 8454144);
  float* denomK = (float*)(ws + 8519680);
  u64*   mask   = (u64*)  (ws + 9568256);
  unsigned short* gTp = (unsigned short*)(ws + 13762560);

  k_mask<<<2048, 256, 0, stream>>>(adj, mask);
  k_h   <<<256, 256, 0, stream>>>(x, W, a1, a2, ab, h, E1, E2p);
  k_den <<<dim3(8, 16, 8), 256, 0, stream>>>(mask, E1, E2p, denomK);
  k_gt  <<<dim3(8, 4, 8), 256, 0, stream>>>(h, denomK, gTp);
  k_main<<<dim3(64, 8), 256, 0, stream>>>(E1, E2p, (const uint32*)mask, gTp, out);
}

// Round 13
// 80.954 us; speedup vs baseline: 1.0538x; 1.0538x over previous
//
#include <hip/hip_runtime.h>
#include <stdint.h>

typedef unsigned int  uint32;
typedef unsigned long long u64;
typedef unsigned char u8;

#define L2E 1.44269504088896340736f

typedef float f32x4 __attribute__((ext_vector_type(4)));
typedef short bf16x8 __attribute__((ext_vector_type(8)));

__device__ __forceinline__ unsigned short f2bf(float f){
  uint32 u = __float_as_uint(f);
  u += 0x7fffu + ((u >> 16) & 1u);
  return (unsigned short)(u >> 16);
}

// k-permutation: k' -> j:  Q = k'>>8, p = (k'>>6)&3, l = k'&63, j = Q*256 + 4*l + p
// byte mask: mb[row*512 + jb] bit p  <->  adj[row][4*jb + p]   (jb = Q*64 + l)
// so mb[n] (n = f32x4 index of adj) = pack of adj[4n..4n+3].
// gTp fragment layout: element (b, o, k') at
//   ((b*64 + (k'>>5))*8 + (o>>4))*512 + (((k'>>3)&3)*16 + (o&15))*8 + (k'&7)

// ---------------- K0: pure per-lane streaming adj -> byte mask ----------------
// 2048 blocks x 256 thr; 16 iters x 524288 f32x4 = 8,388,608 = all of adj. No cross-lane ops.
__global__ __launch_bounds__(256) void k_maskb(const float* __restrict__ adj,
                                               u8* __restrict__ mb){
  const size_t t = (size_t)blockIdx.x * 256 + threadIdx.x;   // 0..524287
  const f32x4* ap = (const f32x4*)adj;
  #pragma unroll 8
  for (int it = 0; it < 16; ++it){
    size_t n = (size_t)it * 524288 + t;
    f32x4 av = ap[n];
    uint32 bByte = (av[0] != 0.f ? 1u : 0u) | (av[1] != 0.f ? 2u : 0u)
                 | (av[2] != 0.f ? 4u : 0u) | (av[3] != 0.f ? 8u : 0u);
    mb[n] = (u8)bByte;
  }
}

// ---------------- K1: h = x @ W^T (bf16 split MFMA) + fused E1/E2p epilogue ----------------
__global__ __launch_bounds__(256) void k_h(const float* __restrict__ x,
                                           const float* __restrict__ W,
                                           const float* __restrict__ a1,
                                           const float* __restrict__ a2,
                                           const float* __restrict__ ab,
                                           float* __restrict__ h,
                                           float* __restrict__ E1,
                                           float* __restrict__ E2p){
  __shared__ unsigned short xs[2][64][72];    // [hi/lo][row][f] pad 72
  __shared__ unsigned short wsm[2][128][72];  // [hi/lo][o][f]
  const int tid = threadIdx.x;
  const int wv = tid >> 6, lane = tid & 63;
  const int r = lane & 15, kg = lane >> 4;
  const int row0 = blockIdx.x * 64;

  f32x4 acc[8];
  #pragma unroll
  for (int of = 0; of < 8; ++of) acc[of] = (f32x4){0.f,0.f,0.f,0.f};

  for (int kc = 0; kc < 4; ++kc){
    if (kc) __syncthreads();
    #pragma unroll
    for (int it = 0; it < 4; ++it){
      int idx = tid + it * 256;
      int row = idx >> 4, f = (idx & 15) * 4;
      float4 v = *(const float4*)(x + (size_t)(row0 + row) * 256 + kc * 64 + f);
      ushort4 hi, lo;
      { unsigned short hh = f2bf(v.x); float rr = v.x - __uint_as_float(((uint32)hh)<<16); hi.x = hh; lo.x = f2bf(rr); }
      { unsigned short hh = f2bf(v.y); float rr = v.y - __uint_as_float(((uint32)hh)<<16); hi.y = hh; lo.y = f2bf(rr); }
      { unsigned short hh = f2bf(v.z); float rr = v.z - __uint_as_float(((uint32)hh)<<16); hi.z = hh; lo.z = f2bf(rr); }
      { unsigned short hh = f2bf(v.w); float rr = v.w - __uint_as_float(((uint32)hh)<<16); hi.w = hh; lo.w = f2bf(rr); }
      *(ushort4*)&xs[0][row][f] = hi;
      *(ushort4*)&xs[1][row][f] = lo;
    }
    #pragma unroll
    for (int it = 0; it < 8; ++it){
      int idx = tid + it * 256;
      int o = idx >> 4, f = (idx & 15) * 4;
      float4 v = *(const float4*)(W + (size_t)o * 256 + kc * 64 + f);
      ushort4 hi, lo;
      { unsigned short hh = f2bf(v.x); float rr = v.x - __uint_as_float(((uint32)hh)<<16); hi.x = hh; lo.x = f2bf(rr); }
      { unsigned short hh = f2bf(v.y); float rr = v.y - __uint_as_float(((uint32)hh)<<16); hi.y = hh; lo.y = f2bf(rr); }
      { unsigned short hh = f2bf(v.z); float rr = v.z - __uint_as_float(((uint32)hh)<<16); hi.z = hh; lo.z = f2bf(rr); }
      { unsigned short hh = f2bf(v.w); float rr = v.w - __uint_as_float(((uint32)hh)<<16); hi.w = hh; lo.w = f2bf(rr); }
      *(ushort4*)&wsm[0][o][f] = hi;
      *(ushort4*)&wsm[1][o][f] = lo;
    }
    __syncthreads();
    #pragma unroll
    for (int kk = 0; kk < 2; ++kk){
      bf16x8 ah = *(const bf16x8*)&xs[0][wv*16 + r][kk*32 + kg*8];
      bf16x8 al = *(const bf16x8*)&xs[1][wv*16 + r][kk*32 + kg*8];
      #pragma unroll
      for (int of = 0; of < 8; ++of){
        bf16x8 bh = *(const bf16x8*)&wsm[0][of*16 + r][kk*32 + kg*8];
        bf16x8 bl = *(const bf16x8*)&wsm[1][of*16 + r][kk*32 + kg*8];
        acc[of] = __builtin_amdgcn_mfma_f32_16x16x32_bf16(ah, bh, acc[of], 0, 0, 0);
        acc[of] = __builtin_amdgcn_mfma_f32_16x16x32_bf16(ah, bl, acc[of], 0, 0, 0);
        acc[of] = __builtin_amdgcn_mfma_f32_16x16x32_bf16(al, bh, acc[of], 0, 0, 0);
      }
    }
  }
  #pragma unroll
  for (int of = 0; of < 8; ++of)
    #pragma unroll
    for (int q = 0; q < 4; ++q)
      h[(size_t)(row0 + wv*16 + kg*4 + q) * 128 + of*16 + r] = acc[of][q];

  float p1[4] = {0,0,0,0}, p2[4] = {0,0,0,0};
  #pragma unroll
  for (int of = 0; of < 8; ++of){
    float w1 = a1[of*16 + r], w2 = a2[of*16 + r];
    #pragma unroll
    for (int q = 0; q < 4; ++q){
      p1[q] = fmaf(acc[of][q], w1, p1[q]);
      p2[q] = fmaf(acc[of][q], w2, p2[q]);
    }
  }
  #pragma unroll
  for (int off = 8; off; off >>= 1)
    #pragma unroll
    for (int q = 0; q < 4; ++q){
      p1[q] += __shfl_xor(p1[q], off);
      p2[q] += __shfl_xor(p2[q], off);
    }
  if (r == 0){
    float abv = ab[0];
    #pragma unroll
    for (int q = 0; q < 4; ++q){
      int row = row0 + wv*16 + kg*4 + q;
      E1[row] = p1[q] * L2E;
      int bb = row >> 11, j = row & 2047;
      int kp = (j & ~255) + (j & 3) * 64 + ((j & 255) >> 2);
      E2p[bb * 2048 + kp] = (p2[q] + abv) * L2E;
    }
  }
}

// ---------------- K2: byte-mask-driven denom partials (k'-order out) ----------------
// grid (c=8, chb=8, b=8); wave wv -> rows (chb*4+wv)*64..+63; lane l -> j = c*256+4l+p.
__global__ __launch_bounds__(256) void k_den(const u8* __restrict__ mb,
                                             const float* __restrict__ E1,
                                             const float* __restrict__ E2p,
                                             float* __restrict__ denomK){
  const int c = blockIdx.x, chb = blockIdx.y, b = blockIdx.z;
  const int wv = threadIdx.x >> 6, lane = threadIdx.x & 63;
  const int ch32 = chb * 4 + wv;
  const int gi0 = b * 2048 + ch32 * 64;

  float e2v[4];
  #pragma unroll
  for (int p = 0; p < 4; ++p)
    e2v[p] = E2p[b * 2048 + c * 256 + p * 64 + lane];

  const float* e1p = E1 + gi0;
  const u8* mp = mb + (size_t)gi0 * 512 + c * 64 + lane;

  float ds0 = 0.f, ds1 = 0.f, ds2 = 0.f, ds3 = 0.f;
  #pragma unroll 8
  for (int i = 0; i < 64; ++i){
    uint32 byte = mp[(size_t)i * 512];
    float e1 = e1p[i];
    float t0 = e1 + e2v[0]; t0 = fmaxf(t0, 0.2f * t0);
    float t1 = e1 + e2v[1]; t1 = fmaxf(t1, 0.2f * t1);
    float t2 = e1 + e2v[2]; t2 = fmaxf(t2, 0.2f * t2);
    float t3 = e1 + e2v[3]; t3 = fmaxf(t3, 0.2f * t3);
    ds0 += (byte & 1u) ? __builtin_amdgcn_exp2f(t0) : 0.f;
    ds1 += (byte & 2u) ? __builtin_amdgcn_exp2f(t1) : 0.f;
    ds2 += (byte & 4u) ? __builtin_amdgcn_exp2f(t2) : 0.f;
    ds3 += (byte & 8u) ? __builtin_amdgcn_exp2f(t3) : 0.f;
  }
  float* dk = denomK + (size_t)ch32 * 16384 + b * 2048 + c * 256;
  dk[0 * 64 + lane] = ds0;
  dk[1 * 64 + lane] = ds1;
  dk[2 * 64 + lane] = ds2;
  dk[3 * 64 + lane] = ds3;
}

// ---------------- K3: gTp[frag-order] = bf16( h[b][j(k')][o] / denom_j ) ----------------
// grid (Q=8, ot=4, b=8); denomK is k'-indexed -> convert j->k' when summing.
__global__ __launch_bounds__(256) void k_gt(const float* __restrict__ h,
                                            const float* __restrict__ denomK,
                                            unsigned short* __restrict__ gTp){
  __shared__ float hl[8464];   // index: j*33 + (j>>4) + oo,  oo<32 (local node order)
  __shared__ float rrec[256];
  const int b = blockIdx.z, Q = blockIdx.x, ot = blockIdx.y;
  const int o0 = ot * 32;
  const int tid = threadIdx.x;

  {
    const int kpl = (tid & 3) * 64 + (tid >> 2);   // k' local of j local = tid
    float d = 0.f;
    #pragma unroll
    for (int ch = 0; ch < 32; ++ch)
      d += denomK[(size_t)ch * 16384 + b * 2048 + Q * 256 + kpl];
    rrec[tid] = 1.0f / d;
  }
  __syncthreads();

  #pragma unroll
  for (int it = 0; it < 8; ++it){
    int idx = tid + it * 256;
    int j = idx >> 3, f = idx & 7;
    float4 v = *(const float4*)(h + (size_t)(b * 2048 + Q * 256 + j) * 128 + o0 + f * 4);
    float rc = rrec[j];
    int base = j * 33 + (j >> 4) + f * 4;
    hl[base + 0] = v.x * rc;
    hl[base + 1] = v.y * rc;
    hl[base + 2] = v.z * rc;
    hl[base + 3] = v.w * rc;
  }
  __syncthreads();

  const int u  = tid & 127;
  const int fh = tid >> 7;
  const int lane = u >> 1;
  const int e0 = (u & 1) * 4;
  const int orow_r = lane & 15;
  const int kgrp = lane >> 4;
  #pragma unroll
  for (int it = 0; it < 8; ++it){
    int f  = it * 2 + fh;
    int kb = f >> 1, sl = f & 1;
    int orow = sl * 16 + orow_r;
    int klb = kb * 32 + kgrp * 8 + e0;
    ushort4 uu;
    { int kl = klb + 0; int jl = 4 * (kl & 63) + (kl >> 6); uu.x = f2bf(hl[jl * 33 + (jl >> 4) + orow]); }
    { int kl = klb + 1; int jl = 4 * (kl & 63) + (kl >> 6); uu.y = f2bf(hl[jl * 33 + (jl >> 4) + orow]); }
    { int kl = klb + 2; int jl = 4 * (kl & 63) + (kl >> 6); uu.z = f2bf(hl[jl * 33 + (jl >> 4) + orow]); }
    { int kl = klb + 3; int jl = 4 * (kl & 63) + (kl >> 6); uu.w = f2bf(hl[jl * 33 + (jl >> 4) + orow]); }
    size_t dst = ((size_t)((b * 64 + Q * 8 + kb) * 8 + (ot * 2 + sl))) * 512 + lane * 8 + e0;
    *(ushort4*)(gTp + dst) = uu;
  }
}

// ---------------- K4: out = ELU( A @ g ), A synthesized from byte mask ----------------
// bit for (row, k'=kk+kg*8+e): u64 at byte row*512 + (kk>>8)*64 + (kk&63) + kg*8,
// bit (e*8 + p) with p = (kk>>6)&3.
__global__ __launch_bounds__(256) void k_main(const float* __restrict__ E1,
                                              const float* __restrict__ E2p,
                                              const u8* __restrict__ mb,
                                              const unsigned short* __restrict__ gTp,
                                              float* __restrict__ out){
  __shared__ float cmb[4][32][129];
  const int b  = blockIdx.y;
  const int ib = blockIdx.x;
  const int wv = threadIdx.x >> 6, lane = threadIdx.x & 63;
  const int r  = lane & 15, kg = lane >> 4;
  const int gi0 = b * 2048 + ib * 32 + r;
  const float e1_0 = E1[gi0];
  const float e1_1 = E1[gi0 + 16];
  const u8* mrow0 = mb + (size_t)gi0 * 512 + kg * 8;
  const u8* mrow1 = mb + (size_t)(gi0 + 16) * 512 + kg * 8;

  f32x4 acc[2][8];
  #pragma unroll
  for (int si = 0; si < 2; ++si)
    #pragma unroll
    for (int so = 0; so < 8; ++so)
      acc[si][so] = (f32x4){0.f, 0.f, 0.f, 0.f};

  const int k0 = wv * 512, k1 = k0 + 512;
  for (int kk = k0; kk < k1; kk += 32){
    const int j0 = kk + kg * 8;     // k'-base for this lane's A fragment
    const float4 eA = *(const float4*)(E2p + b * 2048 + j0);
    const float4 eB = *(const float4*)(E2p + b * 2048 + j0 + 4);
    const int boff = (kk >> 8) * 64 + (kk & 63);
    const int pb = (kk >> 6) & 3;
    const u64 mq0 = *(const u64*)(mrow0 + boff);
    const u64 mq1 = *(const u64*)(mrow1 + boff);
    float e2v[8] = {eA.x, eA.y, eA.z, eA.w, eB.x, eB.y, eB.z, eB.w};

    union { uint32 u[4]; bf16x8 v; } af0, af1;
    #pragma unroll
    for (int p = 0; p < 4; ++p){
      {
        float t0 = e1_0 + e2v[2*p];     t0 = fmaxf(t0, 0.2f * t0);
        float t1 = e1_0 + e2v[2*p+1];   t1 = fmaxf(t1, 0.2f * t1);
        float x0 = ((mq0 >> (2*p*8 + pb)) & 1ull) ? __builtin_amdgcn_exp2f(t0) : 0.f;
        float x1 = ((mq0 >> ((2*p+1)*8 + pb)) & 1ull) ? __builtin_amdgcn_exp2f(t1) : 0.f;
        uint32 u0 = __float_as_uint(x0); u0 = (u0 + 0x7fffu + ((u0 >> 16) & 1u)) >> 16;
        uint32 u1 = __float_as_uint(x1); u1 = (u1 + 0x7fffu + ((u1 >> 16) & 1u)) & 0xffff0000u;
        af0.u[p] = u0 | u1;
      }
      {
        float t0 = e1_1 + e2v[2*p];     t0 = fmaxf(t0, 0.2f * t0);
        float t1 = e1_1 + e2v[2*p+1];   t1 = fmaxf(t1, 0.2f * t1);
        float x0 = ((mq1 >> (2*p*8 + pb)) & 1ull) ? __builtin_amdgcn_exp2f(t0) : 0.f;
        float x1 = ((mq1 >> ((2*p+1)*8 + pb)) & 1ull) ? __builtin_amdgcn_exp2f(t1) : 0.f;
        uint32 u0 = __float_as_uint(x0); u0 = (u0 + 0x7fffu + ((u0 >> 16) & 1u)) >> 16;
        uint32 u1 = __float_as_uint(x1); u1 = (u1 + 0x7fffu + ((u1 >> 16) & 1u)) & 0xffff0000u;
        af1.u[p] = u0 | u1;
      }
    }
    const unsigned short* gk = gTp + ((size_t)(b * 64 + (kk >> 5)) * 8) * 512 + lane * 8;
    #pragma unroll
    for (int so = 0; so < 8; ++so){
      bf16x8 bfr = *(const bf16x8*)(gk + so * 512);
      acc[0][so] = __builtin_amdgcn_mfma_f32_16x16x32_bf16(af0.v, bfr, acc[0][so], 0, 0, 0);
      acc[1][so] = __builtin_amdgcn_mfma_f32_16x16x32_bf16(af1.v, bfr, acc[1][so], 0, 0, 0);
    }
  }

  #pragma unroll
  for (int si = 0; si < 2; ++si)
    #pragma unroll
    for (int so = 0; so < 8; ++so)
      #pragma unroll
      for (int q = 0; q < 4; ++q){
        int il = si * 16 + kg * 4 + q;
        int o  = so * 16 + r;
        cmb[wv][il][o] = acc[si][so][q];
      }
  __syncthreads();
  for (int e = threadIdx.x; e < 4096; e += 256){
    int i = e >> 7, o = e & 127;
    float v = cmb[0][i][o] + cmb[1][i][o] + cmb[2][i][o] + cmb[3][i][o];
    float res = v > 0.f ? v : (__builtin_amdgcn_exp2f(v * L2E) - 1.0f);
    out[(size_t)(b * 2048 + ib * 32 + i) * 128 + o] = res;
  }
}

// ---------------- launch ----------------
extern "C" void kernel_launch(void* const* d_in, const int* in_sizes, int n_in,
                              void* d_out, int out_size, void* d_ws, size_t ws_size,
                              hipStream_t stream){
  const float* x   = (const float*)d_in[0];
  const float* adj = (const float*)d_in[1];
  const float* W   = (const float*)d_in[2];
  const float* a1  = (const float*)d_in[3];
  const float* a2  = (const float*)d_in[4];
  const float* ab  = (const float*)d_in[5];
  float* out = (float*)d_out;

  // ws layout (bytes):
  //   h      f32 [16384*128]      @ 0          (8,388,608)
  //   E1     f32 [16384]          @ 8388608    (65,536)
  //   E2p    f32 [16384]          @ 8454144    (65,536)
  //   denomK f32 [32][16384]      @ 8519680    (2,097,152)
  //   maskB  u8  [16384*512]      @ 10616832   (8,388,608)
  //   gTp    bf16[8*64*8*512]     @ 19005440   (4,194,304)
  const size_t WS_NEEDED = 23199744;
  if (ws_size < WS_NEEDED) return;

  char* ws = (char*)d_ws;
  float* h      = (float*)(ws);
  float* E1     = (float*)(ws + 8388608);
  float* E2p    = (float*)(ws + 8454144);
  float* denomK = (float*)(ws + 8519680);
  u8*    maskB  = (u8*)   (ws + 10616832);
  unsigned short* gTp = (unsigned short*)(ws + 19005440);

  k_maskb<<<2048, 256, 0, stream>>>(adj, maskB);
  k_h    <<<256, 256, 0, stream>>>(x, W, a1, a2, ab, h, E1, E2p);
  k_den  <<<dim3(8, 8, 8), 256, 0, stream>>>(maskB, E1, E2p, denomK);
  k_gt   <<<dim3(8, 4, 8), 256, 0, stream>>>(h, denomK, gTp);
  k_main <<<dim3(64, 8), 256, 0, stream>>>(E1, E2p, maskB, gTp, out);
}

// Round 14
// 68.716 us; speedup vs baseline: 1.2415x; 1.1781x over previous
//
#include <hip/hip_runtime.h>
#include <stdint.h>

typedef unsigned int  uint32;
typedef unsigned long long u64;

#define L2E 1.44269504088896340736f

typedef float f32x4 __attribute__((ext_vector_type(4)));
typedef short bf16x8 __attribute__((ext_vector_type(8)));

__device__ __forceinline__ unsigned short f2bf(float f){
  uint32 u = __float_as_uint(f);
  u += 0x7fffu + ((u >> 16) & 1u);
  return (unsigned short)(u >> 16);
}

// k-permutation: k' -> j:  Q = k'>>8, p = (k'>>6)&3, l = k'&63, j = Q*256 + 4*l + p
// inverse:       j  -> k': Q = j>>8,  l = (j&255)>>2, p = j&3,  k' = Q*256 + p*64 + l
// mask word w of row i: bit l <-> k' = w*64+l <-> j = (w>>2)*256 + 4*l + (w&3)
// gTp fragment layout: element (b, o, k') at
//   ((b*64 + (k'>>5))*8 + (o>>4))*512 + (((k'>>3)&3)*16 + (o&15))*8 + (k'&7)

// ---------------- K1: h = x @ W^T (bf16 split MFMA) + fused E1/E2p epilogue ----------------
__global__ __launch_bounds__(256) void k_h(const float* __restrict__ x,
                                           const float* __restrict__ W,
                                           const float* __restrict__ a1,
                                           const float* __restrict__ a2,
                                           const float* __restrict__ ab,
                                           float* __restrict__ h,
                                           float* __restrict__ E1,
                                           float* __restrict__ E2p){
  __shared__ unsigned short xs[2][64][72];    // [hi/lo][row][f] pad 72
  __shared__ unsigned short wsm[2][128][72];  // [hi/lo][o][f]
  const int tid = threadIdx.x;
  const int wv = tid >> 6, lane = tid & 63;
  const int r = lane & 15, kg = lane >> 4;
  const int row0 = blockIdx.x * 64;

  f32x4 acc[8];
  #pragma unroll
  for (int of = 0; of < 8; ++of) acc[of] = (f32x4){0.f,0.f,0.f,0.f};

  for (int kc = 0; kc < 4; ++kc){
    if (kc) __syncthreads();
    #pragma unroll
    for (int it = 0; it < 4; ++it){
      int idx = tid + it * 256;
      int row = idx >> 4, f = (idx & 15) * 4;
      float4 v = *(const float4*)(x + (size_t)(row0 + row) * 256 + kc * 64 + f);
      ushort4 hi, lo;
      { unsigned short hh = f2bf(v.x); float rr = v.x - __uint_as_float(((uint32)hh)<<16); hi.x = hh; lo.x = f2bf(rr); }
      { unsigned short hh = f2bf(v.y); float rr = v.y - __uint_as_float(((uint32)hh)<<16); hi.y = hh; lo.y = f2bf(rr); }
      { unsigned short hh = f2bf(v.z); float rr = v.z - __uint_as_float(((uint32)hh)<<16); hi.z = hh; lo.z = f2bf(rr); }
      { unsigned short hh = f2bf(v.w); float rr = v.w - __uint_as_float(((uint32)hh)<<16); hi.w = hh; lo.w = f2bf(rr); }
      *(ushort4*)&xs[0][row][f] = hi;
      *(ushort4*)&xs[1][row][f] = lo;
    }
    #pragma unroll
    for (int it = 0; it < 8; ++it){
      int idx = tid + it * 256;
      int o = idx >> 4, f = (idx & 15) * 4;
      float4 v = *(const float4*)(W + (size_t)o * 256 + kc * 64 + f);
      ushort4 hi, lo;
      { unsigned short hh = f2bf(v.x); float rr = v.x - __uint_as_float(((uint32)hh)<<16); hi.x = hh; lo.x = f2bf(rr); }
      { unsigned short hh = f2bf(v.y); float rr = v.y - __uint_as_float(((uint32)hh)<<16); hi.y = hh; lo.y = f2bf(rr); }
      { unsigned short hh = f2bf(v.z); float rr = v.z - __uint_as_float(((uint32)hh)<<16); hi.z = hh; lo.z = f2bf(rr); }
      { unsigned short hh = f2bf(v.w); float rr = v.w - __uint_as_float(((uint32)hh)<<16); hi.w = hh; lo.w = f2bf(rr); }
      *(ushort4*)&wsm[0][o][f] = hi;
      *(ushort4*)&wsm[1][o][f] = lo;
    }
    __syncthreads();
    #pragma unroll
    for (int kk = 0; kk < 2; ++kk){
      bf16x8 ah = *(const bf16x8*)&xs[0][wv*16 + r][kk*32 + kg*8];
      bf16x8 al = *(const bf16x8*)&xs[1][wv*16 + r][kk*32 + kg*8];
      #pragma unroll
      for (int of = 0; of < 8; ++of){
        bf16x8 bh = *(const bf16x8*)&wsm[0][of*16 + r][kk*32 + kg*8];
        bf16x8 bl = *(const bf16x8*)&wsm[1][of*16 + r][kk*32 + kg*8];
        acc[of] = __builtin_amdgcn_mfma_f32_16x16x32_bf16(ah, bh, acc[of], 0, 0, 0);
        acc[of] = __builtin_amdgcn_mfma_f32_16x16x32_bf16(ah, bl, acc[of], 0, 0, 0);
        acc[of] = __builtin_amdgcn_mfma_f32_16x16x32_bf16(al, bh, acc[of], 0, 0, 0);
      }
    }
  }
  #pragma unroll
  for (int of = 0; of < 8; ++of)
    #pragma unroll
    for (int q = 0; q < 4; ++q)
      h[(size_t)(row0 + wv*16 + kg*4 + q) * 128 + of*16 + r] = acc[of][q];

  float p1[4] = {0,0,0,0}, p2[4] = {0,0,0,0};
  #pragma unroll
  for (int of = 0; of < 8; ++of){
    float w1 = a1[of*16 + r], w2 = a2[of*16 + r];
    #pragma unroll
    for (int q = 0; q < 4; ++q){
      p1[q] = fmaf(acc[of][q], w1, p1[q]);
      p2[q] = fmaf(acc[of][q], w2, p2[q]);
    }
  }
  #pragma unroll
  for (int off = 8; off; off >>= 1)
    #pragma unroll
    for (int q = 0; q < 4; ++q){
      p1[q] += __shfl_xor(p1[q], off);
      p2[q] += __shfl_xor(p2[q], off);
    }
  if (r == 0){
    float abv = ab[0];
    #pragma unroll
    for (int q = 0; q < 4; ++q){
      int row = row0 + wv*16 + kg*4 + q;
      E1[row] = p1[q] * L2E;
      int bb = row >> 11, j = row & 2047;
      int kp = (j & ~255) + (j & 3) * 64 + ((j & 255) >> 2);
      E2p[bb * 2048 + kp] = (p2[q] + abv) * L2E;
    }
  }
}

// ---------------- K2: denom partials + mask in k'-order (R3/R9-proven config) ----------------
// grid (Q=8, ic=8, b=8) = 512 blocks, 4 waves/block; wave covers 256 j x 64 i rows, f32x4/lane.
__global__ __launch_bounds__(256) void k_dm(const float* __restrict__ adj,
                                            const float* __restrict__ E1,
                                            const float* __restrict__ E2p,
                                            float* __restrict__ denomP,
                                            u64* __restrict__ mask){
  __shared__ float red[4][256];
  const int b = blockIdx.z, Q = blockIdx.x, ic = blockIdx.y;
  const int wv = threadIdx.x >> 6, lane = threadIdx.x & 63;
  const int Jbase = Q * 256;
  const int row0 = ic * 256 + wv * 64;

  const float* e1p = E1 + b * 2048 + row0;
  const f32x4* ap = (const f32x4*)(adj + (size_t)(b * 2048 + row0) * 2048 + Jbase) + lane;
  u64* mp = mask + (size_t)(b * 2048 + row0) * 32 + Q * 4;

  float e2v[4];
  #pragma unroll
  for (int p = 0; p < 4; ++p)
    e2v[p] = E2p[b * 2048 + Q * 256 + p * 64 + lane];

  float ds0 = 0.f, ds1 = 0.f, ds2 = 0.f, ds3 = 0.f;

  for (int r0 = 0; r0 < 64; r0 += 8){
    f32x4 av[8];
    #pragma unroll
    for (int u = 0; u < 8; ++u)
      av[u] = ap[(size_t)(r0 + u) * 512];
    #pragma unroll
    for (int u = 0; u < 8; ++u){
      const float e1 = e1p[r0 + u];
      float t0 = e1 + e2v[0]; t0 = fmaxf(t0, 0.2f * t0);
      float t1 = e1 + e2v[1]; t1 = fmaxf(t1, 0.2f * t1);
      float t2 = e1 + e2v[2]; t2 = fmaxf(t2, 0.2f * t2);
      float t3 = e1 + e2v[3]; t3 = fmaxf(t3, 0.2f * t3);
      ds0 = fmaf(av[u][0], __builtin_amdgcn_exp2f(t0), ds0);
      ds1 = fmaf(av[u][1], __builtin_amdgcn_exp2f(t1), ds1);
      ds2 = fmaf(av[u][2], __builtin_amdgcn_exp2f(t2), ds2);
      ds3 = fmaf(av[u][3], __builtin_amdgcn_exp2f(t3), ds3);
      u64 b0 = __ballot(av[u][0] != 0.f);
      u64 b1 = __ballot(av[u][1] != 0.f);
      u64 b2 = __ballot(av[u][2] != 0.f);
      u64 b3 = __ballot(av[u][3] != 0.f);
      if (lane == 0){
        ulonglong2* dst = (ulonglong2*)(mp + (size_t)(r0 + u) * 32);
        dst[0] = (ulonglong2){b0, b1};
        dst[1] = (ulonglong2){b2, b3};
      }
    }
  }

  *(float4*)&red[wv][lane * 4] = (float4){ds0, ds1, ds2, ds3};
  __syncthreads();
  const int t = threadIdx.x;
  denomP[(size_t)ic * 16384 + b * 2048 + Jbase + t] = red[0][t] + red[1][t] + red[2][t] + red[3][t];
}

// ---------------- K3: gTp[frag-order] = bf16( h[b][j(k')][o] / denom[j(k')] ) ----------------
// grid (Q=8, ot=4, b=8)
__global__ __launch_bounds__(256) void k_gt(const float* __restrict__ h,
                                            const float* __restrict__ denomP,
                                            unsigned short* __restrict__ gTp){
  __shared__ float hl[8464];   // index: j*33 + (j>>4) + oo,  oo<32 (local node order)
  __shared__ float rrec[256];
  const int b = blockIdx.z, Q = blockIdx.x, ot = blockIdx.y;
  const int o0 = ot * 32;
  const int tid = threadIdx.x;

  {
    float d = 0.f;
    #pragma unroll
    for (int icc = 0; icc < 8; ++icc)
      d += denomP[(size_t)icc * 16384 + b * 2048 + Q * 256 + tid];
    rrec[tid] = 1.0f / d;
  }
  __syncthreads();

  #pragma unroll
  for (int it = 0; it < 8; ++it){
    int idx = tid + it * 256;
    int j = idx >> 3, f = idx & 7;
    float4 v = *(const float4*)(h + (size_t)(b * 2048 + Q * 256 + j) * 128 + o0 + f * 4);
    float rc = rrec[j];
    int base = j * 33 + (j >> 4) + f * 4;
    hl[base + 0] = v.x * rc;
    hl[base + 1] = v.y * rc;
    hl[base + 2] = v.z * rc;
    hl[base + 3] = v.w * rc;
  }
  __syncthreads();

  const int u  = tid & 127;
  const int fh = tid >> 7;
  const int lane = u >> 1;
  const int e0 = (u & 1) * 4;
  const int orow_r = lane & 15;
  const int kgrp = lane >> 4;
  #pragma unroll
  for (int it = 0; it < 8; ++it){
    int f  = it * 2 + fh;
    int kb = f >> 1, sl = f & 1;
    int orow = sl * 16 + orow_r;
    int klb = kb * 32 + kgrp * 8 + e0;
    ushort4 uu;
    { int kl = klb + 0; int jl = 4 * (kl & 63) + (kl >> 6); uu.x = f2bf(hl[jl * 33 + (jl >> 4) + orow]); }
    { int kl = klb + 1; int jl = 4 * (kl & 63) + (kl >> 6); uu.y = f2bf(hl[jl * 33 + (jl >> 4) + orow]); }
    { int kl = klb + 2; int jl = 4 * (kl & 63) + (kl >> 6); uu.z = f2bf(hl[jl * 33 + (jl >> 4) + orow]); }
    { int kl = klb + 3; int jl = 4 * (kl & 63) + (kl >> 6); uu.w = f2bf(hl[jl * 33 + (jl >> 4) + orow]); }
    size_t dst = ((size_t)((b * 64 + Q * 8 + kb) * 8 + (ot * 2 + sl))) * 512 + lane * 8 + e0;
    *(ushort4*)(gTp + dst) = uu;
  }
}

// ---------------- K4: out = ELU( A @ g ), A synthesized, B coalesced frag loads ----------------
__global__ __launch_bounds__(256) void k_main(const float* __restrict__ E1,
                                              const float* __restrict__ E2p,
                                              const uint32* __restrict__ mask32,
                                              const unsigned short* __restrict__ gTp,
                                              float* __restrict__ out){
  __shared__ float cmb[4][32][129];
  const int b  = blockIdx.y;
  const int ib = blockIdx.x;
  const int wv = threadIdx.x >> 6, lane = threadIdx.x & 63;
  const int r  = lane & 15, kg = lane >> 4;
  const int gi0 = b * 2048 + ib * 32 + r;
  const float e1_0 = E1[gi0];
  const float e1_1 = E1[gi0 + 16];
  const uint32* m0 = mask32 + (size_t)gi0 * 64;
  const uint32* m1 = mask32 + (size_t)(gi0 + 16) * 64;

  f32x4 acc[2][8];
  #pragma unroll
  for (int si = 0; si < 2; ++si)
    #pragma unroll
    for (int so = 0; so < 8; ++so)
      acc[si][so] = (f32x4){0.f, 0.f, 0.f, 0.f};

  const int k0 = wv * 512, k1 = k0 + 512;
  for (int kk = k0; kk < k1; kk += 32){
    const int j0 = kk + kg * 8;
    const float4 eA = *(const float4*)(E2p + b * 2048 + j0);
    const float4 eB = *(const float4*)(E2p + b * 2048 + j0 + 4);
    const uint32 bits0 = (m0[kk >> 5] >> (kg * 8)) & 0xffu;
    const uint32 bits1 = (m1[kk >> 5] >> (kg * 8)) & 0xffu;
    float e2v[8] = {eA.x, eA.y, eA.z, eA.w, eB.x, eB.y, eB.z, eB.w};

    union { uint32 u[4]; bf16x8 v; } af0, af1;
    #pragma unroll
    for (int p = 0; p < 4; ++p){
      {
        float t0 = e1_0 + e2v[2*p];     t0 = fmaxf(t0, 0.2f * t0);
        float t1 = e1_0 + e2v[2*p+1];   t1 = fmaxf(t1, 0.2f * t1);
        float x0 = ((bits0 >> (2*p))   & 1u) ? __builtin_amdgcn_exp2f(t0) : 0.f;
        float x1 = ((bits0 >> (2*p+1)) & 1u) ? __builtin_amdgcn_exp2f(t1) : 0.f;
        uint32 u0 = __float_as_uint(x0); u0 = (u0 + 0x7fffu + ((u0 >> 16) & 1u)) >> 16;
        uint32 u1 = __float_as_uint(x1); u1 = (u1 + 0x7fffu + ((u1 >> 16) & 1u)) & 0xffff0000u;
        af0.u[p] = u0 | u1;
      }
      {
        float t0 = e1_1 + e2v[2*p];     t0 = fmaxf(t0, 0.2f * t0);
        float t1 = e1_1 + e2v[2*p+1];   t1 = fmaxf(t1, 0.2f * t1);
        float x0 = ((bits1 >> (2*p))   & 1u) ? __builtin_amdgcn_exp2f(t0) : 0.f;
        float x1 = ((bits1 >> (2*p+1)) & 1u) ? __builtin_amdgcn_exp2f(t1) : 0.f;
        uint32 u0 = __float_as_uint(x0); u0 = (u0 + 0x7fffu + ((u0 >> 16) & 1u)) >> 16;
        uint32 u1 = __float_as_uint(x1); u1 = (u1 + 0x7fffu + ((u1 >> 16) & 1u)) & 0xffff0000u;
        af1.u[p] = u0 | u1;
      }
    }
    const unsigned short* gk = gTp + ((size_t)(b * 64 + (kk >> 5)) * 8) * 512 + lane * 8;
    #pragma unroll
    for (int so = 0; so < 8; ++so){
      bf16x8 bfr = *(const bf16x8*)(gk + so * 512);
      acc[0][so] = __builtin_amdgcn_mfma_f32_16x16x32_bf16(af0.v, bfr, acc[0][so], 0, 0, 0);
      acc[1][so] = __builtin_amdgcn_mfma_f32_16x16x32_bf16(af1.v, bfr, acc[1][so], 0, 0, 0);
    }
  }

  #pragma unroll
  for (int si = 0; si < 2; ++si)
    #pragma unroll
    for (int so = 0; so < 8; ++so)
      #pragma unroll
      for (int q = 0; q < 4; ++q){
        int il = si * 16 + kg * 4 + q;
        int o  = so * 16 + r;
        cmb[wv][il][o] = acc[si][so][q];
      }
  __syncthreads();
  for (int e = threadIdx.x; e < 4096; e += 256){
    int i = e >> 7, o = e & 127;
    float v = cmb[0][i][o] + cmb[1][i][o] + cmb[2][i][o] + cmb[3][i][o];
    float res = v > 0.f ? v : (__builtin_amdgcn_exp2f(v * L2E) - 1.0f);
    out[(size_t)(b * 2048 + ib * 32 + i) * 128 + o] = res;
  }
}

// ---------------- launch ----------------
extern "C" void kernel_launch(void* const* d_in, const int* in_sizes, int n_in,
                              void* d_out, int out_size, void* d_ws, size_t ws_size,
                              hipStream_t stream){
  const float* x   = (const float*)d_in[0];
  const float* adj = (const float*)d_in[1];
  const float* W   = (const float*)d_in[2];
  const float* a1  = (const float*)d_in[3];
  const float* a2  = (const float*)d_in[4];
  const float* ab  = (const float*)d_in[5];
  float* out = (float*)d_out;

  // ws layout (bytes):
  //   h      f32 [16384*128]      @ 0          (8,388,608)
  //   E1     f32 [16384]          @ 8388608    (65,536)
  //   E2p    f32 [16384]          @ 8454144    (65,536)
  //   denomP f32 [8][16384]       @ 8519680    (524,288)
  //   mask   u64 [8*2048*32]      @ 9043968    (4,194,304)
  //   gTp    bf16[8*64*8*512]     @ 13238272   (4,194,304)
  const size_t WS_NEEDED = 17432576;
  if (ws_size < WS_NEEDED) return;

  char* ws = (char*)d_ws;
  float* h      = (float*)(ws);
  float* E1     = (float*)(ws + 8388608);
  float* E2p    = (float*)(ws + 8454144);
  float* denomP = (float*)(ws + 8519680);
  u64*   mask   = (u64*)  (ws + 9043968);
  unsigned short* gTp = (unsigned short*)(ws + 13238272);

  k_h  <<<256, 256, 0, stream>>>(x, W, a1, a2, ab, h, E1, E2p);
  k_dm <<<dim3(8, 8, 8), 256, 0, stream>>>(adj, E1, E2p, denomP, mask);
  k_gt <<<dim3(8, 4, 8), 256, 0, stream>>>(h, denomP, gTp);
  k_main<<<dim3(64, 8), 256, 0, stream>>>(E1, E2p, (const uint32*)mask, gTp, out);
}